// Round 1
// baseline (614.947 us; speedup 1.0000x reference)
//
#include <hip/hip_runtime.h>
#include <hip/hip_bf16.h>

#define N_TOK 16384
#define DM 1024
#define HD 512
#define NE 8
#define LN_EPS 1e-5f

typedef __attribute__((ext_vector_type(8))) short v8s;   // 8 bf16 (4 VGPRs)
typedef __attribute__((ext_vector_type(4))) float v4f;

__device__ __forceinline__ unsigned short f2bf(float f) {
  union { float f; unsigned u; } c; c.f = f;
  unsigned u = c.u + 0x7FFFu + ((c.u >> 16) & 1u);   // RNE
  return (unsigned short)(u >> 16);
}

__device__ __forceinline__ float gelu_f(float v) {
  return 0.5f * v * (1.0f + erff(v * 0.7071067811865475f));
}

// ---------------- gate: LN -> logits -> softmax -> top2 ----------------
__global__ __launch_bounds__(256) void gate_kernel(
    const float* __restrict__ x, const float* __restrict__ lnw,
    const float* __restrict__ lnb, const float* __restrict__ gw,
    const float* __restrict__ gb, float* __restrict__ gates_out,
    int* __restrict__ ce, float* __restrict__ cw)
{
  const int wv = threadIdx.x >> 6, l = threadIdx.x & 63;
  const int n = blockIdx.x * 4 + wv;
  const float* xr = x + (size_t)n * DM;
  float4 v[4]; float s = 0.f, s2 = 0.f;
#pragma unroll
  for (int j = 0; j < 4; ++j) {
    v[j] = *(const float4*)(xr + l * 4 + j * 256);
    s  += v[j].x + v[j].y + v[j].z + v[j].w;
    s2 += v[j].x * v[j].x + v[j].y * v[j].y + v[j].z * v[j].z + v[j].w * v[j].w;
  }
#pragma unroll
  for (int m = 1; m < 64; m <<= 1) { s += __shfl_xor(s, m); s2 += __shfl_xor(s2, m); }
  const float mu = s * (1.f / DM);
  const float var = s2 * (1.f / DM) - mu * mu;
  const float rstd = 1.f / sqrtf(var + LN_EPS);
  float acc[8] = {0, 0, 0, 0, 0, 0, 0, 0};
#pragma unroll
  for (int j = 0; j < 4; ++j) {
#pragma unroll
    for (int q = 0; q < 4; ++q) {
      int d = l * 4 + j * 256 + q;
      float xv = (q == 0) ? v[j].x : (q == 1) ? v[j].y : (q == 2) ? v[j].z : v[j].w;
      float xn = (xv - mu) * rstd * lnw[d] + lnb[d];
      const float4 g0 = *(const float4*)(gw + d * 8);
      const float4 g1 = *(const float4*)(gw + d * 8 + 4);
      acc[0] += xn * g0.x; acc[1] += xn * g0.y; acc[2] += xn * g0.z; acc[3] += xn * g0.w;
      acc[4] += xn * g1.x; acc[5] += xn * g1.y; acc[6] += xn * g1.z; acc[7] += xn * g1.w;
    }
  }
#pragma unroll
  for (int e = 0; e < 8; ++e)
#pragma unroll
    for (int m = 1; m < 64; m <<= 1) acc[e] += __shfl_xor(acc[e], m);

  if (l == 0) {
    float lg[8], p[8], g[8];
    float mx = -1e30f;
    for (int e = 0; e < 8; ++e) { lg[e] = acc[e] + gb[e]; mx = fmaxf(mx, lg[e]); }
    float sum = 0.f;
    for (int e = 0; e < 8; ++e) { p[e] = expf(lg[e] - mx); sum += p[e]; }
    float inv = 1.f / sum;
    for (int e = 0; e < 8; ++e) g[e] = p[e] * inv;
    float4* go = (float4*)(gates_out + (size_t)n * 8);
    go[0] = make_float4(g[0], g[1], g[2], g[3]);
    go[1] = make_float4(g[4], g[5], g[6], g[7]);
    int e0 = 0; float b0 = g[0];
    for (int e = 1; e < 8; ++e) if (g[e] > b0) { b0 = g[e]; e0 = e; }   // low idx wins tie
    int e1 = -1; float b1v = -1.f;
    for (int e = 0; e < 8; ++e) if (e != e0 && g[e] > b1v) { b1v = g[e]; e1 = e; }
    float wsum = b0 + b1v;
    ce[2 * n] = e0; ce[2 * n + 1] = e1;
    cw[2 * n] = b0 / wsum; cw[2 * n + 1] = b1v / wsum;
  }
}

// ---------------- route: compact per-expert token lists ----------------
__global__ __launch_bounds__(256) void route_kernel(
    const int* __restrict__ ce, const float* __restrict__ cw,
    int* __restrict__ counts, int* __restrict__ tids, float* __restrict__ pws)
{
  __shared__ int cnt;
  const int e = blockIdx.x;
  if (threadIdx.x == 0) cnt = 0;
  __syncthreads();
  for (int i = threadIdx.x; i < 2 * N_TOK; i += 256) {
    if (ce[i] == e) {
      int p = atomicAdd(&cnt, 1);
      tids[e * N_TOK + p] = i >> 1;
      pws[e * N_TOK + p] = cw[i];
    }
  }
  __syncthreads();
  if (threadIdx.x == 0) counts[e] = cnt;
}

// -------- transpose + fp32->bf16: in [E][R][C] f32 -> out [E][C][R] bf16 --------
__global__ __launch_bounds__(256) void transpose_cvt(
    const float* __restrict__ in, unsigned short* __restrict__ out, int R, int C)
{
  __shared__ float tile[64][65];
  const int tilesC = C >> 6, tilesR = R >> 6;
  const int perE = tilesR * tilesC;
  int bt = blockIdx.x;
  const int e = bt / perE; int rem = bt - e * perE;
  const int tr = rem / tilesC, tc = rem - tr * tilesC;
  const float* ip = in + (size_t)e * R * C;
  unsigned short* op = out + (size_t)e * R * C;
  const int r0 = tr * 64, c0 = tc * 64;
#pragma unroll
  for (int i = 0; i < 16; ++i) {
    int idx = i * 256 + threadIdx.x;
    int rr = idx >> 6, cc = idx & 63;
    tile[rr][cc] = ip[(size_t)(r0 + rr) * C + (c0 + cc)];
  }
  __syncthreads();
#pragma unroll
  for (int i = 0; i < 16; ++i) {
    int idx = i * 256 + threadIdx.x;
    int rr = idx >> 6, cc = idx & 63;
    op[(size_t)(c0 + rr) * R + (r0 + cc)] = f2bf(tile[cc][rr]);
  }
}

// ---------------- fused grouped expert FFN ----------------
// LDS map (dynamic, 139776 B):
//   h_tile   @ 0       : [64 tok][512 h] bf16, row 1024 B, XOR-swizzled
//   xs       @ 65536   : [64 tok][64 k] bf16, row 128 B   (phase 1)
//   w1s      @ 73728   : [512 h][64 k] bf16, row 128 B    (phase 1)
//   w2s      @ 65536   : [256 d][64 h] bf16, row 128 B    (phase 2, overlaps xs/w1s)
//   tok/wt   @ 139264 / 139520
#define H_OFF   0
#define XS_OFF  65536
#define W1S_OFF 73728
#define W2S_OFF 65536
#define TOK_OFF 139264
#define WT_OFF  139520
#define SMEM_BYTES 139776

template<bool FULL>
__global__ __launch_bounds__(512, 2) void ffn_kernel(
    const float* __restrict__ x,
    const float* __restrict__ w1, const float* __restrict__ b1,
    const float* __restrict__ w2, const float* __restrict__ b2,
    const unsigned short* __restrict__ w1t, const unsigned short* __restrict__ w2t,
    const int* __restrict__ counts, const int* __restrict__ tids,
    const float* __restrict__ pws, float* __restrict__ outp)
{
  extern __shared__ char smem[];
  const int e = blockIdx.x & 7;          // expert -> XCD affinity
  const int tile = blockIdx.x >> 3;
  const int cnt = counts[e];
  const int base = tile * 64;
  if (base >= cnt) return;
  const int t = threadIdx.x;
  const int w = t >> 6, l = t & 63;
  const int lrow = l & 15, lhi = l >> 4;

  int* tokL = (int*)(smem + TOK_OFF);
  float* wtL = (float*)(smem + WT_OFF);
  if (t < 64) {
    int i = base + t;
    bool ok = i < cnt;
    int src = e * N_TOK + (ok ? i : base);
    tokL[t] = tids[src];
    wtL[t] = ok ? pws[src] : 0.f;
  }
  __syncthreads();

  // ---- phase 1: h_tile = gelu(X @ W1 + b1) ----
  v4f acc[4][4];
#pragma unroll
  for (int a = 0; a < 4; ++a)
#pragma unroll
    for (int b = 0; b < 4; ++b) acc[a][b] = (v4f){0.f, 0.f, 0.f, 0.f};

  for (int kt = 0; kt < 16; ++kt) {
    const int k0 = kt * 64;
    {  // stage xs (gathered token rows, fp32 -> bf16)
      const int tokr = t >> 3, ks = t & 7;
      const float* src = x + (size_t)tokL[tokr] * DM + k0 + ks * 8;
      float f[8];
      *(float4*)(f) = *(const float4*)src;
      *(float4*)(f + 4) = *(const float4*)(src + 4);
      v8s pv;
#pragma unroll
      for (int j = 0; j < 8; ++j) pv[j] = (short)f2bf(f[j]);
      *(v8s*)(smem + XS_OFF + tokr * 128 + ((ks ^ (tokr & 7)) << 4)) = pv;
    }
    if (FULL) {  // stage w1s from pre-transposed bf16
#pragma unroll
      for (int i = 0; i < 8; ++i) {
        int c = i * 512 + t;
        int h = c >> 3, ks = c & 7;
        v8s val = *(const v8s*)(w1t + ((size_t)e * HD + h) * DM + k0 + ks * 8);
        *(v8s*)(smem + W1S_OFF + h * 128 + ((ks ^ (h & 7)) << 4)) = val;
      }
    } else {     // fallback: strided fp32 reads (coalesced across threads per j)
      const int h = t;
#pragma unroll
      for (int i = 0; i < 8; ++i) {
        float f[8];
#pragma unroll
        for (int j = 0; j < 8; ++j) f[j] = w1[((size_t)e * DM + k0 + i * 8 + j) * HD + h];
        v8s pv;
#pragma unroll
        for (int j = 0; j < 8; ++j) pv[j] = (short)f2bf(f[j]);
        *(v8s*)(smem + W1S_OFF + h * 128 + ((i ^ (h & 7)) << 4)) = pv;
      }
    }
    __syncthreads();
#pragma unroll
    for (int ks2 = 0; ks2 < 2; ++ks2) {
      const int sb = (ks2 << 2) + lhi;
      v8s af[4], bfr[4];
#pragma unroll
      for (int mi = 0; mi < 4; ++mi) {
        int row = mi * 16 + lrow;
        af[mi] = *(const v8s*)(smem + XS_OFF + row * 128 + ((sb ^ (row & 7)) << 4));
      }
#pragma unroll
      for (int nj = 0; nj < 4; ++nj) {
        int col = (w << 6) + nj * 16 + lrow;
        bfr[nj] = *(const v8s*)(smem + W1S_OFF + col * 128 + ((sb ^ (col & 7)) << 4));
      }
#pragma unroll
      for (int mi = 0; mi < 4; ++mi)
#pragma unroll
        for (int nj = 0; nj < 4; ++nj)
          acc[mi][nj] = __builtin_amdgcn_mfma_f32_16x16x32_bf16(af[mi], bfr[nj], acc[mi][nj], 0, 0, 0);
    }
    __syncthreads();
  }

  // epilogue: +b1, gelu, pack to h_tile
#pragma unroll
  for (int nj = 0; nj < 4; ++nj) {
    const int col = (w << 6) + nj * 16 + lrow;
    const float b1v = b1[e * HD + col];
#pragma unroll
    for (int mi = 0; mi < 4; ++mi) {
#pragma unroll
      for (int r = 0; r < 4; ++r) {
        int row = mi * 16 + lhi * 4 + r;
        float g = gelu_f(acc[mi][nj][r] + b1v);
        *(unsigned short*)(smem + H_OFF + row * 1024 + ((col * 2) ^ ((row & 7) << 4))) = f2bf(g);
      }
    }
  }
  __syncthreads();

  // ---- phase 2: out += wt * (h_tile @ W2 + b2) ----
  for (int nc = 0; nc < 4; ++nc) {
    v4f acc2[4][2];
#pragma unroll
    for (int a = 0; a < 4; ++a)
#pragma unroll
      for (int b = 0; b < 2; ++b) acc2[a][b] = (v4f){0.f, 0.f, 0.f, 0.f};
    for (int k2 = 0; k2 < 8; ++k2) {
      const int h0 = k2 * 64;
      if (FULL) {
#pragma unroll
        for (int i = 0; i < 4; ++i) {
          int c = i * 512 + t;
          int dloc = c >> 3, ks = c & 7;
          v8s val = *(const v8s*)(w2t + ((size_t)e * DM + nc * 256 + dloc) * HD + h0 + ks * 8);
          *(v8s*)(smem + W2S_OFF + dloc * 128 + ((ks ^ (dloc & 7)) << 4)) = val;
        }
      } else {
        const int dloc = t & 255;
        const int kb = t >> 8;
#pragma unroll
        for (int i = 0; i < 4; ++i) {
          int ks = kb + i * 2;
          float f[8];
#pragma unroll
          for (int j = 0; j < 8; ++j) f[j] = w2[((size_t)e * HD + h0 + ks * 8 + j) * DM + nc * 256 + dloc];
          v8s pv;
#pragma unroll
          for (int j = 0; j < 8; ++j) pv[j] = (short)f2bf(f[j]);
          *(v8s*)(smem + W2S_OFF + dloc * 128 + ((ks ^ (dloc & 7)) << 4)) = pv;
        }
      }
      __syncthreads();
#pragma unroll
      for (int ks2 = 0; ks2 < 2; ++ks2) {
        const int sb = (ks2 << 2) + lhi;
        v8s af[4], bfr[2];
#pragma unroll
        for (int mi = 0; mi < 4; ++mi) {
          int row = mi * 16 + lrow;
          int slin = (h0 >> 3) + sb;
          af[mi] = *(const v8s*)(smem + H_OFF + row * 1024 + ((slin ^ (row & 7)) << 4));
        }
#pragma unroll
        for (int nj = 0; nj < 2; ++nj) {
          int dl = (w << 5) + nj * 16 + lrow;
          bfr[nj] = *(const v8s*)(smem + W2S_OFF + dl * 128 + ((sb ^ (dl & 7)) << 4));
        }
#pragma unroll
        for (int mi = 0; mi < 4; ++mi)
#pragma unroll
          for (int nj = 0; nj < 2; ++nj)
            acc2[mi][nj] = __builtin_amdgcn_mfma_f32_16x16x32_bf16(af[mi], bfr[nj], acc2[mi][nj], 0, 0, 0);
      }
      __syncthreads();
    }
    // scatter-accumulate weighted output
#pragma unroll
    for (int nj = 0; nj < 2; ++nj) {
      const int dl = (w << 5) + nj * 16 + lrow;
      const int d = nc * 256 + dl;
      const float b2v = b2[e * DM + d];
#pragma unroll
      for (int mi = 0; mi < 4; ++mi) {
#pragma unroll
        for (int r = 0; r < 4; ++r) {
          int row = mi * 16 + lhi * 4 + r;
          float val = wtL[row] * (acc2[mi][nj][r] + b2v);
          atomicAdd(outp + (size_t)tokL[row] * DM + d, val);
        }
      }
    }
  }
}

// ---------------- launch ----------------
extern "C" void kernel_launch(void* const* d_in, const int* in_sizes, int n_in,
                              void* d_out, int out_size, void* d_ws, size_t ws_size,
                              hipStream_t stream)
{
  const float* x   = (const float*)d_in[0];
  const float* lnw = (const float*)d_in[1];
  const float* lnb = (const float*)d_in[2];
  const float* gw  = (const float*)d_in[3];
  const float* gb  = (const float*)d_in[4];
  const float* w1  = (const float*)d_in[5];
  const float* b1  = (const float*)d_in[6];
  const float* w2  = (const float*)d_in[7];
  const float* b2  = (const float*)d_in[8];
  float* out = (float*)d_out;
  float* gates_out = out + (size_t)N_TOK * DM;

  char* ws = (char*)d_ws;
  int*   ce     = (int*)(ws + 0);          // int[2N]
  float* cw     = (float*)(ws + 131072);   // float[2N]
  int*   counts = (int*)(ws + 262144);     // int[8]
  int*   tids   = (int*)(ws + 262400);     // int[8*N]
  float* pws    = (float*)(ws + 786688);   // float[8*N]
  unsigned short* w1t = (unsigned short*)(ws + 1310976);  // bf16 [E][H][D]
  unsigned short* w2t = (unsigned short*)(ws + 9699584);  // bf16 [E][D][H]
  const bool full = ws_size >= 18088192ull;

  hipMemsetAsync(d_out, 0, (size_t)N_TOK * DM * sizeof(float), stream);
  gate_kernel<<<N_TOK / 4, 256, 0, stream>>>(x, lnw, lnb, gw, gb, gates_out, ce, cw);
  route_kernel<<<NE, 256, 0, stream>>>(ce, cw, counts, tids, pws);
  if (full) {
    transpose_cvt<<<NE * 16 * 8, 256, 0, stream>>>(w1, w1t, DM, HD);
    transpose_cvt<<<NE * 8 * 16, 256, 0, stream>>>(w2, w2t, HD, DM);
    hipFuncSetAttribute((const void*)&ffn_kernel<true>,
                        hipFuncAttributeMaxDynamicSharedMemorySize, SMEM_BYTES);
    ffn_kernel<true><<<NE * 256, 512, SMEM_BYTES, stream>>>(
        x, w1, b1, w2, b2, w1t, w2t, counts, tids, pws, out);
  } else {
    hipFuncSetAttribute((const void*)&ffn_kernel<false>,
                        hipFuncAttributeMaxDynamicSharedMemorySize, SMEM_BYTES);
    ffn_kernel<false><<<NE * 256, 512, SMEM_BYTES, stream>>>(
        x, w1, b1, w2, b2, w1t, w2t, counts, tids, pws, out);
  }
}

// Round 3
// 506.777 us; speedup vs baseline: 1.2134x; 1.2134x over previous
//
#include <hip/hip_runtime.h>
#include <hip/hip_bf16.h>

#define N_TOK 16384
#define DM 1024
#define HD 512
#define NE 8
#define LN_EPS 1e-5f
#define MT_MAX 264   // max sum of ceil(cnt_e/128) = 256 + 7 (load-balance independent)

typedef __attribute__((ext_vector_type(8))) short v8s;   // 8 bf16 (4 VGPRs)
typedef __attribute__((ext_vector_type(4))) float v4f;

typedef const __attribute__((address_space(1))) unsigned int* as1cu;
typedef __attribute__((address_space(3))) unsigned int* as3u;

__device__ __forceinline__ void gl_lds16(const void* g, void* l) {
  // async global->LDS, 16B per lane; LDS dest = wave-uniform base + lane*16
  __builtin_amdgcn_global_load_lds((as1cu)g, (as3u)l, 16, 0, 0);
}

__device__ __forceinline__ unsigned short f2bf(float f) {
  union { float f; unsigned u; } c; c.f = f;
  unsigned u = c.u + 0x7FFFu + ((c.u >> 16) & 1u);   // RNE
  return (unsigned short)(u >> 16);
}

__device__ __forceinline__ float gelu_f(float v) {
  return 0.5f * v * (1.0f + erff(v * 0.7071067811865475f));
}

// ---------------- gate: LN -> logits -> softmax -> top2 (+ x -> bf16) ----------------
__global__ __launch_bounds__(256) void gate_kernel(
    const float* __restrict__ x, const float* __restrict__ lnw,
    const float* __restrict__ lnb, const float* __restrict__ gw,
    const float* __restrict__ gb, float* __restrict__ gates_out,
    int* __restrict__ ce, float* __restrict__ cw,
    unsigned short* __restrict__ xbf)
{
  const int wv = threadIdx.x >> 6, l = threadIdx.x & 63;
  const int n = blockIdx.x * 4 + wv;
  const float* xr = x + (size_t)n * DM;
  float4 v[4]; float s = 0.f, s2 = 0.f;
#pragma unroll
  for (int j = 0; j < 4; ++j) {
    v[j] = *(const float4*)(xr + l * 4 + j * 256);
    s  += v[j].x + v[j].y + v[j].z + v[j].w;
    s2 += v[j].x * v[j].x + v[j].y * v[j].y + v[j].z * v[j].z + v[j].w * v[j].w;
  }
  if (xbf) {   // emit bf16 copy of x for the FFN A-tiles
    unsigned long long* xbo = (unsigned long long*)(xbf + (size_t)n * DM);
#pragma unroll
    for (int j = 0; j < 4; ++j) {
      union { unsigned short u[4]; unsigned long long ll; } pk;
      pk.u[0] = f2bf(v[j].x); pk.u[1] = f2bf(v[j].y);
      pk.u[2] = f2bf(v[j].z); pk.u[3] = f2bf(v[j].w);
      xbo[l + j * 64] = pk.ll;
    }
  }
#pragma unroll
  for (int m = 1; m < 64; m <<= 1) { s += __shfl_xor(s, m); s2 += __shfl_xor(s2, m); }
  const float mu = s * (1.f / DM);
  const float var = s2 * (1.f / DM) - mu * mu;
  const float rstd = 1.f / sqrtf(var + LN_EPS);
  float acc[8] = {0, 0, 0, 0, 0, 0, 0, 0};
#pragma unroll
  for (int j = 0; j < 4; ++j) {
#pragma unroll
    for (int q = 0; q < 4; ++q) {
      int d = l * 4 + j * 256 + q;
      float xv = (q == 0) ? v[j].x : (q == 1) ? v[j].y : (q == 2) ? v[j].z : v[j].w;
      float xn = (xv - mu) * rstd * lnw[d] + lnb[d];
      const float4 g0 = *(const float4*)(gw + d * 8);
      const float4 g1 = *(const float4*)(gw + d * 8 + 4);
      acc[0] += xn * g0.x; acc[1] += xn * g0.y; acc[2] += xn * g0.z; acc[3] += xn * g0.w;
      acc[4] += xn * g1.x; acc[5] += xn * g1.y; acc[6] += xn * g1.z; acc[7] += xn * g1.w;
    }
  }
#pragma unroll
  for (int e = 0; e < 8; ++e)
#pragma unroll
    for (int m = 1; m < 64; m <<= 1) acc[e] += __shfl_xor(acc[e], m);

  if (l == 0) {
    float lg[8], p[8], g[8];
    float mx = -1e30f;
    for (int e = 0; e < 8; ++e) { lg[e] = acc[e] + gb[e]; mx = fmaxf(mx, lg[e]); }
    float sum = 0.f;
    for (int e = 0; e < 8; ++e) { p[e] = expf(lg[e] - mx); sum += p[e]; }
    float inv = 1.f / sum;
    for (int e = 0; e < 8; ++e) g[e] = p[e] * inv;
    float4* go = (float4*)(gates_out + (size_t)n * 8);
    go[0] = make_float4(g[0], g[1], g[2], g[3]);
    go[1] = make_float4(g[4], g[5], g[6], g[7]);
    int e0 = 0; float b0 = g[0];
    for (int e = 1; e < 8; ++e) if (g[e] > b0) { b0 = g[e]; e0 = e; }   // low idx wins tie
    int e1 = -1; float b1v = -1.f;
    for (int e = 0; e < 8; ++e) if (e != e0 && g[e] > b1v) { b1v = g[e]; e1 = e; }
    float wsum = b0 + b1v;
    ce[2 * n] = e0; ce[2 * n + 1] = e1;
    cw[2 * n] = b0 / wsum; cw[2 * n + 1] = b1v / wsum;
  }
}

// ---------------- route: compact per-expert token lists ----------------
__global__ __launch_bounds__(256) void route_kernel(
    const int* __restrict__ ce, const float* __restrict__ cw,
    int* __restrict__ counts, int* __restrict__ tids, float* __restrict__ pws)
{
  __shared__ int cnt;
  const int e = blockIdx.x;
  if (threadIdx.x == 0) cnt = 0;
  __syncthreads();
  for (int i = threadIdx.x; i < 2 * N_TOK; i += 256) {
    if (ce[i] == e) {
      int p = atomicAdd(&cnt, 1);
      tids[e * N_TOK + p] = i >> 1;
      pws[e * N_TOK + p] = cw[i];
    }
  }
  __syncthreads();
  if (threadIdx.x == 0) counts[e] = cnt;
}

// -------- transpose + fp32->bf16: in [E][R][C] f32 -> out [E][C][R] bf16 --------
__global__ __launch_bounds__(256) void transpose_cvt(
    const float* __restrict__ in, unsigned short* __restrict__ out, int R, int C)
{
  __shared__ float tile[64][65];
  const int tilesC = C >> 6, tilesR = R >> 6;
  const int perE = tilesR * tilesC;
  int bt = blockIdx.x;
  const int e = bt / perE; int rem = bt - e * perE;
  const int tr = rem / tilesC, tc = rem - tr * tilesC;
  const float* ip = in + (size_t)e * R * C;
  unsigned short* op = out + (size_t)e * R * C;
  const int r0 = tr * 64, c0 = tc * 64;
#pragma unroll
  for (int i = 0; i < 16; ++i) {
    int idx = i * 256 + threadIdx.x;
    int rr = idx >> 6, cc = idx & 63;
    tile[rr][cc] = ip[(size_t)(r0 + rr) * C + (c0 + cc)];
  }
  __syncthreads();
#pragma unroll
  for (int i = 0; i < 16; ++i) {
    int idx = i * 256 + threadIdx.x;
    int rr = idx >> 6, cc = idx & 63;
    op[(size_t)(c0 + rr) * R + (r0 + cc)] = f2bf(tile[cc][rr]);
  }
}

// ================= grouped GEMM 1: hbuf = gelu(Xgather @ W1^T + b1) =================
// m97 structure: 128x128 tile, BK=64, 4 waves (2x2), global_load_lds w/ pre-swizzled
// global addresses, XOR-swizzled ds_read_b128, 2 barriers per K-step.
__global__ __launch_bounds__(256, 3) void gemm1_kernel(
    const unsigned short* __restrict__ xbf, const unsigned short* __restrict__ w1t,
    const float* __restrict__ b1,
    const int* __restrict__ counts, const int* __restrict__ tids,
    unsigned short* __restrict__ hbuf)
{
  __shared__ unsigned short As[128 * 64];   // 16 KB, rows of 128 B
  __shared__ unsigned short Bs[128 * 64];   // 16 KB
  __shared__ int tokL[128];
  __shared__ int sE, sBase, sCnt;

  const int t = threadIdx.x;
  const int bid = blockIdx.x;
  const int nt = bid / MT_MAX;              // 0..3 (h-col tile)
  const int mt = bid - nt * MT_MAX;         // global m-tile

  if (t == 0) {
    int pref = 0, e = -1, base = 0, cn = 0;
    for (int i = 0; i < NE; ++i) {
      int c = counts[i];
      int tiles = (c + 127) >> 7;
      if (mt < pref + tiles) { e = i; base = (mt - pref) << 7; cn = c; break; }
      pref += tiles;
    }
    sE = e; sBase = base; sCnt = cn;
  }
  __syncthreads();
  const int e = sE;
  if (e < 0) return;
  const int cnt = sCnt, baseI = sBase;

  if (t < 128) {
    int i = baseI + t;
    tokL[t] = (i < cnt) ? tids[e * N_TOK + i] : tids[e * N_TOK];  // clamp pad rows
  }
  __syncthreads();

  // per-thread fixed staging sources (pre-swizzled k-block so LDS stays linear)
  const unsigned short* gA[4];
  const unsigned short* gB[4];
#pragma unroll
  for (int i = 0; i < 4; ++i) {
    int c = i * 256 + t;
    int row = c >> 3, ks = c & 7;
    int kswz = ks ^ (row & 7);
    gA[i] = xbf + (size_t)tokL[row] * DM + kswz * 8;
    gB[i] = w1t + ((size_t)e * HD + nt * 128 + row) * DM + kswz * 8;
  }
  const int w = t >> 6, l = t & 63;
  const int wr = w >> 1, wc = w & 1;
  const int lrow = l & 15, lhi = l >> 4;
  char* AsB = (char*)As;
  char* BsB = (char*)Bs;
  char* ldsA = AsB + w * 1024;
  char* ldsB = BsB + w * 1024;

  v4f acc[4][4];
#pragma unroll
  for (int a = 0; a < 4; ++a)
#pragma unroll
    for (int b = 0; b < 4; ++b) acc[a][b] = (v4f){0.f, 0.f, 0.f, 0.f};

  for (int kt = 0; kt < 16; ++kt) {
    __syncthreads();                        // prev compute done before overwrite
#pragma unroll
    for (int i = 0; i < 4; ++i) {
      gl_lds16(gA[i] + kt * 64, ldsA + i * 4096);
      gl_lds16(gB[i] + kt * 64, ldsB + i * 4096);
    }
    __syncthreads();                        // staging visible (drains vmcnt)
#pragma unroll
    for (int ks2 = 0; ks2 < 2; ++ks2) {
      const int sb = ks2 * 4 + lhi;
      v8s a[4], b[4];
#pragma unroll
      for (int mi = 0; mi < 4; ++mi) {
        int row = wr * 64 + mi * 16 + lrow;
        a[mi] = *(const v8s*)(AsB + row * 128 + ((sb ^ (row & 7)) << 4));
      }
#pragma unroll
      for (int nj = 0; nj < 4; ++nj) {
        int col = wc * 64 + nj * 16 + lrow;
        b[nj] = *(const v8s*)(BsB + col * 128 + ((sb ^ (col & 7)) << 4));
      }
#pragma unroll
      for (int mi = 0; mi < 4; ++mi)
#pragma unroll
        for (int nj = 0; nj < 4; ++nj)
          acc[mi][nj] = __builtin_amdgcn_mfma_f32_16x16x32_bf16(a[mi], b[nj], acc[mi][nj], 0, 0, 0);
    }
  }

  // epilogue: + b1, gelu, bf16 store to hbuf[slot][h]
#pragma unroll
  for (int nj = 0; nj < 4; ++nj) {
    const int col = nt * 128 + wc * 64 + nj * 16 + lrow;
    const float bb = b1[e * HD + col];
#pragma unroll
    for (int mi = 0; mi < 4; ++mi) {
      const int row0 = wr * 64 + mi * 16 + lhi * 4;
#pragma unroll
      for (int r = 0; r < 4; ++r) {
        float g = gelu_f(acc[mi][nj][r] + bb);
        hbuf[(size_t)(mt * 128 + row0 + r) * HD + col] = f2bf(g);
      }
    }
  }
}

// ================= grouped GEMM 2: out += wt * (hbuf @ W2^T + b2) =================
__global__ __launch_bounds__(256, 3) void gemm2_kernel(
    const unsigned short* __restrict__ hbuf, const unsigned short* __restrict__ w2t,
    const float* __restrict__ b2,
    const int* __restrict__ counts, const int* __restrict__ tids,
    const float* __restrict__ pws, float* __restrict__ outp)
{
  __shared__ unsigned short As[128 * 64];
  __shared__ unsigned short Bs[128 * 64];
  __shared__ int tokL[128];
  __shared__ float wtL[128];
  __shared__ int sE, sBase, sCnt;

  const int t = threadIdx.x;
  const int bid = blockIdx.x;
  const int nt = bid / MT_MAX;              // 0..7 (d-col tile)
  const int mt = bid - nt * MT_MAX;

  if (t == 0) {
    int pref = 0, e = -1, base = 0, cn = 0;
    for (int i = 0; i < NE; ++i) {
      int c = counts[i];
      int tiles = (c + 127) >> 7;
      if (mt < pref + tiles) { e = i; base = (mt - pref) << 7; cn = c; break; }
      pref += tiles;
    }
    sE = e; sBase = base; sCnt = cn;
  }
  __syncthreads();
  const int e = sE;
  if (e < 0) return;
  const int cnt = sCnt, baseI = sBase;

  if (t < 128) {
    int i = baseI + t;
    bool ok = i < cnt;
    tokL[t] = ok ? tids[e * N_TOK + i] : 0;
    wtL[t] = ok ? pws[e * N_TOK + i] : 0.f;
  }
  __syncthreads();

  const unsigned short* gA[4];
  const unsigned short* gB[4];
#pragma unroll
  for (int i = 0; i < 4; ++i) {
    int c = i * 256 + t;
    int row = c >> 3, ks = c & 7;
    int kswz = ks ^ (row & 7);
    gA[i] = hbuf + (size_t)(mt * 128 + row) * HD + kswz * 8;
    gB[i] = w2t + ((size_t)e * DM + nt * 128 + row) * HD + kswz * 8;
  }
  const int w = t >> 6, l = t & 63;
  const int wr = w >> 1, wc = w & 1;
  const int lrow = l & 15, lhi = l >> 4;
  char* AsB = (char*)As;
  char* BsB = (char*)Bs;
  char* ldsA = AsB + w * 1024;
  char* ldsB = BsB + w * 1024;

  v4f acc[4][4];
#pragma unroll
  for (int a = 0; a < 4; ++a)
#pragma unroll
    for (int b = 0; b < 4; ++b) acc[a][b] = (v4f){0.f, 0.f, 0.f, 0.f};

  for (int kt = 0; kt < 8; ++kt) {          // K = HD = 512
    __syncthreads();
#pragma unroll
    for (int i = 0; i < 4; ++i) {
      gl_lds16(gA[i] + kt * 64, ldsA + i * 4096);
      gl_lds16(gB[i] + kt * 64, ldsB + i * 4096);
    }
    __syncthreads();
#pragma unroll
    for (int ks2 = 0; ks2 < 2; ++ks2) {
      const int sb = ks2 * 4 + lhi;
      v8s a[4], b[4];
#pragma unroll
      for (int mi = 0; mi < 4; ++mi) {
        int row = wr * 64 + mi * 16 + lrow;
        a[mi] = *(const v8s*)(AsB + row * 128 + ((sb ^ (row & 7)) << 4));
      }
#pragma unroll
      for (int nj = 0; nj < 4; ++nj) {
        int col = wc * 64 + nj * 16 + lrow;
        b[nj] = *(const v8s*)(BsB + col * 128 + ((sb ^ (col & 7)) << 4));
      }
#pragma unroll
      for (int mi = 0; mi < 4; ++mi)
#pragma unroll
        for (int nj = 0; nj < 4; ++nj)
          acc[mi][nj] = __builtin_amdgcn_mfma_f32_16x16x32_bf16(a[mi], b[nj], acc[mi][nj], 0, 0, 0);
    }
  }

  // epilogue: weighted atomic combine into out[token][d]
#pragma unroll
  for (int nj = 0; nj < 4; ++nj) {
    const int col = nt * 128 + wc * 64 + nj * 16 + lrow;
    const float bb = b2[e * DM + col];
#pragma unroll
    for (int mi = 0; mi < 4; ++mi) {
      const int rbase = wr * 64 + mi * 16 + lhi * 4;
#pragma unroll
      for (int r = 0; r < 4; ++r) {
        const int rloc = rbase + r;
        if (baseI + rloc < cnt) {
          float val = wtL[rloc] * (acc[mi][nj][r] + bb);
          atomicAdd(outp + (size_t)tokL[rloc] * DM + col, val);
        }
      }
    }
  }
}

// ================== legacy fused FFN (fallback tiers, unchanged) ==================
#define H_OFF   0
#define XS_OFF  65536
#define W1S_OFF 73728
#define W2S_OFF 65536
#define TOK_OFF 139264
#define WT_OFF  139520
#define SMEM_BYTES 139776

template<bool FULL>
__global__ __launch_bounds__(512, 2) void ffn_kernel(
    const float* __restrict__ x,
    const float* __restrict__ w1, const float* __restrict__ b1,
    const float* __restrict__ w2, const float* __restrict__ b2,
    const unsigned short* __restrict__ w1t, const unsigned short* __restrict__ w2t,
    const int* __restrict__ counts, const int* __restrict__ tids,
    const float* __restrict__ pws, float* __restrict__ outp)
{
  extern __shared__ char smem[];
  const int e = blockIdx.x & 7;
  const int tile = blockIdx.x >> 3;
  const int cnt = counts[e];
  const int base = tile * 64;
  if (base >= cnt) return;
  const int t = threadIdx.x;
  const int w = t >> 6, l = t & 63;
  const int lrow = l & 15, lhi = l >> 4;

  int* tokL = (int*)(smem + TOK_OFF);
  float* wtL = (float*)(smem + WT_OFF);
  if (t < 64) {
    int i = base + t;
    bool ok = i < cnt;
    int src = e * N_TOK + (ok ? i : base);
    tokL[t] = tids[src];
    wtL[t] = ok ? pws[src] : 0.f;
  }
  __syncthreads();

  v4f acc[4][4];
#pragma unroll
  for (int a = 0; a < 4; ++a)
#pragma unroll
    for (int b = 0; b < 4; ++b) acc[a][b] = (v4f){0.f, 0.f, 0.f, 0.f};

  for (int kt = 0; kt < 16; ++kt) {
    const int k0 = kt * 64;
    {
      const int tokr = t >> 3, ks = t & 7;
      const float* src = x + (size_t)tokL[tokr] * DM + k0 + ks * 8;
      float f[8];
      *(float4*)(f) = *(const float4*)src;
      *(float4*)(f + 4) = *(const float4*)(src + 4);
      v8s pv;
#pragma unroll
      for (int j = 0; j < 8; ++j) pv[j] = (short)f2bf(f[j]);
      *(v8s*)(smem + XS_OFF + tokr * 128 + ((ks ^ (tokr & 7)) << 4)) = pv;
    }
    if (FULL) {
#pragma unroll
      for (int i = 0; i < 8; ++i) {
        int c = i * 512 + t;
        int h = c >> 3, ks = c & 7;
        v8s val = *(const v8s*)(w1t + ((size_t)e * HD + h) * DM + k0 + ks * 8);
        *(v8s*)(smem + W1S_OFF + h * 128 + ((ks ^ (h & 7)) << 4)) = val;
      }
    } else {
      const int h = t;
#pragma unroll
      for (int i = 0; i < 8; ++i) {
        float f[8];
#pragma unroll
        for (int j = 0; j < 8; ++j) f[j] = w1[((size_t)e * DM + k0 + i * 8 + j) * HD + h];
        v8s pv;
#pragma unroll
        for (int j = 0; j < 8; ++j) pv[j] = (short)f2bf(f[j]);
        *(v8s*)(smem + W1S_OFF + h * 128 + ((i ^ (h & 7)) << 4)) = pv;
      }
    }
    __syncthreads();
#pragma unroll
    for (int ks2 = 0; ks2 < 2; ++ks2) {
      const int sb = (ks2 << 2) + lhi;
      v8s af[4], bfr[4];
#pragma unroll
      for (int mi = 0; mi < 4; ++mi) {
        int row = mi * 16 + lrow;
        af[mi] = *(const v8s*)(smem + XS_OFF + row * 128 + ((sb ^ (row & 7)) << 4));
      }
#pragma unroll
      for (int nj = 0; nj < 4; ++nj) {
        int col = (w << 6) + nj * 16 + lrow;
        bfr[nj] = *(const v8s*)(smem + W1S_OFF + col * 128 + ((sb ^ (col & 7)) << 4));
      }
#pragma unroll
      for (int mi = 0; mi < 4; ++mi)
#pragma unroll
        for (int nj = 0; nj < 4; ++nj)
          acc[mi][nj] = __builtin_amdgcn_mfma_f32_16x16x32_bf16(af[mi], bfr[nj], acc[mi][nj], 0, 0, 0);
    }
    __syncthreads();
  }

#pragma unroll
  for (int nj = 0; nj < 4; ++nj) {
    const int col = (w << 6) + nj * 16 + lrow;
    const float b1v = b1[e * HD + col];
#pragma unroll
    for (int mi = 0; mi < 4; ++mi) {
#pragma unroll
      for (int r = 0; r < 4; ++r) {
        int row = mi * 16 + lhi * 4 + r;
        float g = gelu_f(acc[mi][nj][r] + b1v);
        *(unsigned short*)(smem + H_OFF + row * 1024 + ((col * 2) ^ ((row & 7) << 4))) = f2bf(g);
      }
    }
  }
  __syncthreads();

  for (int nc = 0; nc < 4; ++nc) {
    v4f acc2[4][2];
#pragma unroll
    for (int a = 0; a < 4; ++a)
#pragma unroll
      for (int b = 0; b < 2; ++b) acc2[a][b] = (v4f){0.f, 0.f, 0.f, 0.f};
    for (int k2 = 0; k2 < 8; ++k2) {
      const int h0 = k2 * 64;
      if (FULL) {
#pragma unroll
        for (int i = 0; i < 4; ++i) {
          int c = i * 512 + t;
          int dloc = c >> 3, ks = c & 7;
          v8s val = *(const v8s*)(w2t + ((size_t)e * DM + nc * 256 + dloc) * HD + h0 + ks * 8);
          *(v8s*)(smem + W2S_OFF + dloc * 128 + ((ks ^ (dloc & 7)) << 4)) = val;
        }
      } else {
        const int dloc = t & 255;
        const int kb = t >> 8;
#pragma unroll
        for (int i = 0; i < 4; ++i) {
          int ks = kb + i * 2;
          float f[8];
#pragma unroll
          for (int j = 0; j < 8; ++j) f[j] = w2[((size_t)e * HD + h0 + ks * 8 + j) * DM + nc * 256 + dloc];
          v8s pv;
#pragma unroll
          for (int j = 0; j < 8; ++j) pv[j] = (short)f2bf(f[j]);
          *(v8s*)(smem + W2S_OFF + dloc * 128 + ((ks ^ (dloc & 7)) << 4)) = pv;
        }
      }
      __syncthreads();
#pragma unroll
      for (int ks2 = 0; ks2 < 2; ++ks2) {
        const int sb = (ks2 << 2) + lhi;
        v8s af[4], bfr[2];
#pragma unroll
        for (int mi = 0; mi < 4; ++mi) {
          int row = mi * 16 + lrow;
          int slin = (h0 >> 3) + sb;
          af[mi] = *(const v8s*)(smem + H_OFF + row * 1024 + ((slin ^ (row & 7)) << 4));
        }
#pragma unroll
        for (int nj = 0; nj < 2; ++nj) {
          int dl = (w << 5) + nj * 16 + lrow;
          bfr[nj] = *(const v8s*)(smem + W2S_OFF + dl * 128 + ((sb ^ (dl & 7)) << 4));
        }
#pragma unroll
        for (int mi = 0; mi < 4; ++mi)
#pragma unroll
          for (int nj = 0; nj < 2; ++nj)
            acc2[mi][nj] = __builtin_amdgcn_mfma_f32_16x16x32_bf16(af[mi], bfr[nj], acc2[mi][nj], 0, 0, 0);
      }
      __syncthreads();
    }
#pragma unroll
    for (int nj = 0; nj < 2; ++nj) {
      const int dl = (w << 5) + nj * 16 + lrow;
      const int d = nc * 256 + dl;
      const float b2v = b2[e * DM + d];
#pragma unroll
      for (int mi = 0; mi < 4; ++mi) {
#pragma unroll
        for (int r = 0; r < 4; ++r) {
          int row = mi * 16 + lhi * 4 + r;
          float val = wtL[row] * (acc2[mi][nj][r] + b2v);
          atomicAdd(outp + (size_t)tokL[row] * DM + d, val);
        }
      }
    }
  }
}

// ---------------- launch ----------------
extern "C" void kernel_launch(void* const* d_in, const int* in_sizes, int n_in,
                              void* d_out, int out_size, void* d_ws, size_t ws_size,
                              hipStream_t stream)
{
  const float* x   = (const float*)d_in[0];
  const float* lnw = (const float*)d_in[1];
  const float* lnb = (const float*)d_in[2];
  const float* gw  = (const float*)d_in[3];
  const float* gb  = (const float*)d_in[4];
  const float* w1  = (const float*)d_in[5];
  const float* b1  = (const float*)d_in[6];
  const float* w2  = (const float*)d_in[7];
  const float* b2  = (const float*)d_in[8];
  float* out = (float*)d_out;
  float* gates_out = out + (size_t)N_TOK * DM;

  char* ws = (char*)d_ws;
  int*   ce     = (int*)(ws + 0);          // int[2N]
  float* cw     = (float*)(ws + 131072);   // float[2N]
  int*   counts = (int*)(ws + 262144);     // int[8]
  int*   tids   = (int*)(ws + 262400);     // int[8*N]
  float* pws    = (float*)(ws + 786688);   // float[8*N]
  unsigned short* w1t = (unsigned short*)(ws + 1310976);   // bf16 [E][H][D]
  unsigned short* w2t = (unsigned short*)(ws + 9699584);   // bf16 [E][D][H]
  unsigned short* xbf = (unsigned short*)(ws + 18088192);  // bf16 [N][D]
  unsigned short* hbuf = (unsigned short*)(ws + 51642624); // bf16 [264*128][H]
  const size_t NEED_NEW = 86245632ull;
  const size_t NEED_FULL = 18088192ull;

  hipMemsetAsync(d_out, 0, (size_t)N_TOK * DM * sizeof(float), stream);

  if (ws_size >= NEED_NEW) {
    gate_kernel<<<N_TOK / 4, 256, 0, stream>>>(x, lnw, lnb, gw, gb, gates_out, ce, cw, xbf);
    route_kernel<<<NE, 256, 0, stream>>>(ce, cw, counts, tids, pws);
    transpose_cvt<<<NE * 16 * 8, 256, 0, stream>>>(w1, w1t, DM, HD);
    transpose_cvt<<<NE * 8 * 16, 256, 0, stream>>>(w2, w2t, HD, DM);
    gemm1_kernel<<<4 * MT_MAX, 256, 0, stream>>>(xbf, w1t, b1, counts, tids, hbuf);
    gemm2_kernel<<<8 * MT_MAX, 256, 0, stream>>>(hbuf, w2t, b2, counts, tids, pws, out);
  } else {
    gate_kernel<<<N_TOK / 4, 256, 0, stream>>>(x, lnw, lnb, gw, gb, gates_out, ce, cw, nullptr);
    route_kernel<<<NE, 256, 0, stream>>>(ce, cw, counts, tids, pws);
    if (ws_size >= NEED_FULL) {
      transpose_cvt<<<NE * 16 * 8, 256, 0, stream>>>(w1, w1t, DM, HD);
      transpose_cvt<<<NE * 8 * 16, 256, 0, stream>>>(w2, w2t, HD, DM);
      hipFuncSetAttribute((const void*)&ffn_kernel<true>,
                          hipFuncAttributeMaxDynamicSharedMemorySize, SMEM_BYTES);
      ffn_kernel<true><<<NE * 256, 512, SMEM_BYTES, stream>>>(
          x, w1, b1, w2, b2, w1t, w2t, counts, tids, pws, out);
    } else {
      hipFuncSetAttribute((const void*)&ffn_kernel<false>,
                          hipFuncAttributeMaxDynamicSharedMemorySize, SMEM_BYTES);
      ffn_kernel<false><<<NE * 256, 512, SMEM_BYTES, stream>>>(
          x, w1, b1, w2, b2, w1t, w2t, counts, tids, pws, out);
    }
  }
}